// Round 18
// baseline (57.054 us; speedup 1.0000x reference)
//
#include <hip/hip_runtime.h>

// Laplacian3D: ZERO-BARRIER wave-private staging.
// Each wave owns a private LDS region (10240 B): 6 own-slots (4 rows, plane P
// staged @P-5, fill-read @P-4, center/w/y-own @P) + 2 halo-slots (8 rows:
// 4 above + 4 below, staged @P-1, y-taps @P). Every LDS byte a wave reads was
// DMA'd by its OWN global_load_lds -> ordering = own-wave counted vmcnt only.
// No s_barrier anywhere; waves free-run. Edge waves (v=0/v=15) issue
// duplicate own-row GLDs in place of invalid halo GLDs -> uniform 3 GLD +
// 1 store per wave-step -> exact vmcnt literals (steady VMW(4)). Invalid halo
// rows pre-zeroed once (never staged over) -> y-masks eliminated.
// 16 waves x 10240 B = 163840 B = all 160 KiB; 256 blocks x 1024 thr.

#define PLANEF 4096
#define WSTRIDE 2560                    // floats per wave region
#define OWNLIT(P) (((P) % 6) * 256)     // own slot base (floats, rel. wave)
#define HALOLIT(P) (1536 + ((P) % 2) * 512)

typedef float fx4 __attribute__((ext_vector_type(4)));

#define GLD(gsrc, ldst) __builtin_amdgcn_global_load_lds(                      \
    (const __attribute__((address_space(1))) unsigned int*)(gsrc),             \
    (__attribute__((address_space(3))) unsigned int*)(ldst), 16, 0, 0)

#define VMW(N) asm volatile("s_waitcnt vmcnt(" #N ")" ::: "memory")

#define F4E(v, j) ((j) == 0 ? (v).x : (j) == 1 ? (v).y : (j) == 2 ? (v).z : (v).w)

// One z-step at absolute plane Z (literal). NW = vmcnt immediate; HO = stage
// own rows of plane Z+5; HH = stage halo rows of plane Z+1; FZ = fill is zero.
// A0 = plane Z-4 on entry, plane Z+4 on exit. A2..A6 = Z-2,Z-1,Z,Z+1,Z+2.
#define STEP(Z, NW, HO, HH, FZ, A0, A1, A2, A3, A4, A5, A6, A7)                \
  {                                                                            \
    if (HO) GLD(vol + (size_t)((Z) + 5) * PLANEF + foff,                       \
                &lds[wb + OWNLIT((Z) + 5)]);                                   \
    if (HH) {                                                                  \
      GLD(vol + (size_t)((Z) + 1) * PLANEF + srcA,                             \
          &lds[wb + (v0 ? OWNLIT((Z) + 1) : HALOLIT((Z) + 1))]);               \
      GLD(vol + (size_t)((Z) + 1) * PLANEF + srcB,                             \
          &lds[wb + (v15 ? OWNLIT((Z) + 1) : HALOLIT((Z) + 1) + 256)]);        \
    }                                                                          \
    VMW(NW);                                                                   \
    const float4 zm4 = A0;                                                     \
    A0 = (FZ) ? zero : *(const float4*)(&lds[fb + OWNLIT((Z) + 4)]);           \
    const float4 zp4 = A0;                                                     \
    const float4 zm2 = A2, zm1 = A3, ctr = A4, zp1 = A5, zp2 = A6;             \
    const int ob = OWNLIT(Z), hb = HALOLIT(Z);                                 \
    const float4 wm = *(const float4*)(&lds[wmoff + ob]);                      \
    const float4 wp = *(const float4*)(&lds[wpoff + ob]);                      \
    const float4 ym4t = *(const float4*)(&lds[yb[0] + (ys[0] ? ob : hb)]);     \
    const float4 ym2t = *(const float4*)(&lds[yb[1] + (ys[1] ? ob : hb)]);     \
    const float4 ym1t = *(const float4*)(&lds[yb[2] + (ys[2] ? ob : hb)]);     \
    const float4 yp1t = *(const float4*)(&lds[yb[3] + (ys[3] ? ob : hb)]);     \
    const float4 yp2t = *(const float4*)(&lds[yb[4] + (ys[4] ? ob : hb)]);     \
    const float4 yp4t = *(const float4*)(&lds[yb[5] + (ys[5] ? ob : hb)]);     \
    const float win[12] = {wm.x * wmm, wm.y * wmm, wm.z * wmm, wm.w * wmm,     \
                           ctr.x, ctr.y, ctr.z, ctr.w,                         \
                           wp.x * wpm, wp.y * wpm, wp.z * wpm, wp.w * wpm};    \
    fx4 o;                                                                     \
    _Pragma("unroll")                                                          \
    for (int j = 0; j < 4; ++j) {                                              \
        const float s1 = F4E(zm1, j) + F4E(zp1, j) + win[3 + j] + win[5 + j]   \
                       + F4E(ym1t, j) + F4E(yp1t, j);                          \
        const float s2 = F4E(zm2, j) + F4E(zp2, j) + win[2 + j] + win[6 + j]   \
                       + F4E(ym2t, j) + F4E(yp2t, j);                          \
        const float s4 = F4E(zm4, j) + F4E(zp4, j) + win[j] + win[8 + j]       \
                       + F4E(ym4t, j) + F4E(yp4t, j);                          \
        o[j] = km6 * win[4 + j] + k1 * s1 + k2 * s2 + k4 * s4;                 \
    }                                                                          \
    __builtin_nontemporal_store(                                               \
        o, (fx4*)(ovol + (size_t)(Z) * PLANEF + foff));                        \
  }

#define S0(Z,NW,HO,HH,FZ) STEP(Z,NW,HO,HH,FZ, a0,a1,a2,a3,a4,a5,a6,a7)
#define S1(Z,NW,HO,HH,FZ) STEP(Z,NW,HO,HH,FZ, a1,a2,a3,a4,a5,a6,a7,a0)
#define S2(Z,NW,HO,HH,FZ) STEP(Z,NW,HO,HH,FZ, a2,a3,a4,a5,a6,a7,a0,a1)
#define S3(Z,NW,HO,HH,FZ) STEP(Z,NW,HO,HH,FZ, a3,a4,a5,a6,a7,a0,a1,a2)
#define S4(Z,NW,HO,HH,FZ) STEP(Z,NW,HO,HH,FZ, a4,a5,a6,a7,a0,a1,a2,a3)
#define S5(Z,NW,HO,HH,FZ) STEP(Z,NW,HO,HH,FZ, a5,a6,a7,a0,a1,a2,a3,a4)
#define S6(Z,NW,HO,HH,FZ) STEP(Z,NW,HO,HH,FZ, a6,a7,a0,a1,a2,a3,a4,a5)
#define S7(Z,NW,HO,HH,FZ) STEP(Z,NW,HO,HH,FZ, a7,a0,a1,a2,a3,a4,a5,a6)

// prologue: register ring (planes Z0-4..Z0+3 from global), stage own planes
// Z0..Z0+4, halo plane Z0; single full drain (once per block, never again).
#define PROLOGUE(Z0)                                                           \
    float4 a0, a1, a2, a3, a4, a5, a6, a7;                                     \
    {                                                                          \
        float4* rr[8] = {&a0, &a1, &a2, &a3, &a4, &a5, &a6, &a7};              \
        _Pragma("unroll")                                                      \
        for (int i = 0; i < 8; ++i)                                            \
            *rr[i] = ((Z0) - 4 + i >= 0)                                       \
                ? *(const float4*)(vol + (size_t)((Z0) - 4 + i) * PLANEF + foff) \
                : zero;                                                        \
    }                                                                          \
    _Pragma("unroll")                                                          \
    for (int i = 0; i < 5; ++i)                                                \
        GLD(vol + (size_t)((Z0) + i) * PLANEF + foff,                          \
            &lds[wb + (((Z0) + i) % 6) * 256]);                                \
    GLD(vol + (size_t)(Z0) * PLANEF + srcA,                                    \
        &lds[wb + (v0 ? OWNLIT(Z0) : HALOLIT(Z0))]);                           \
    GLD(vol + (size_t)(Z0) * PLANEF + srcB,                                    \
        &lds[wb + (v15 ? OWNLIT(Z0) : HALOLIT(Z0) + 256)]);                    \
    VMW(0);

__global__ __launch_bounds__(1024) void lap3d_nobar(
    const float* __restrict__ x, const float* __restrict__ p,
    float* __restrict__ out)
{
    __shared__ __align__(16) float lds[40960];   // 163840 B = 160 KiB

    const int tid   = threadIdx.x;
    const int bc    = blockIdx.x & 127;       // b*64 + c
    const int chunk = blockIdx.x >> 7;
    const int c     = bc & 63;

    const float* vol  = x   + (size_t)bc * (64 * PLANEF);
    float*       ovol = out + (size_t)bc * (64 * PLANEF);

    const int lane = tid & 63;
    const int v    = tid >> 6;                // wave id 0..15
    const int yr   = (tid >> 4) & 3;          // row within wave (0..3)
    const int w0   = (tid & 15) << 2;
    const int foff = tid << 2;                // own column in plane (floats)
    const int wb   = v * WSTRIDE;             // wave region base (floats)
    const bool v0 = (v == 0), v15 = (v == 15);

    // halo staging sources (plane-relative float offsets); edge waves use a
    // benign duplicate of their own rows (same bytes, valid address).
    const int srcA = v0  ? foff : foff - 256;  // rows 4v-4..4v-1 (above)
    const int srcB = v15 ? foff : foff + 256;  // rows 4v+4..4v+7 (below)

    const float k1  = 0.25f / (1.0f + __expf(-p[c]));
    const float k2  = 0.25f / (1.0f + __expf(-p[64 + c]));
    const float k4  = 0.25f / (1.0f + __expf(-p[128 + c]));
    const float km6 = -6.0f * (k1 + k2 + k4);

    // fill read base (own slot, own row/col)
    const int fb = wb + yr * 64 + w0;

    // w-taps (own slot, clamped + masked)
    const bool  wmv = (w0 >= 4), wpv = (w0 <= 56);
    const int   wmoff = wb + yr * 64 + (wmv ? w0 - 4 : w0);
    const int   wpoff = wb + yr * 64 + (wpv ? w0 + 4 : w0);
    const float wmm = wmv ? 1.0f : 0.0f, wpm = wpv ? 1.0f : 0.0f;

    // y-taps: r = yr+dy in [-4,7]; own rows 0..3 -> own slot; else halo slot
    // (above rows at halo rows 0..3 = r+4, below at halo rows 4..7 = r).
    // Invalid halo rows hold zeros -> NO masks.
    const int dys[6] = {-4, -2, -1, 1, 2, 4};
    int yb[6]; bool ys[6];
#pragma unroll
    for (int k = 0; k < 6; ++k) {
        const int r = yr + dys[k];
        const bool own = (r >= 0 && r < 4);
        const int rowoff = own ? r * 64 + w0
                               : ((r < 0 ? r + 4 : r) * 64 + w0);
        yb[k] = wb + rowoff;
        ys[k] = own;
    }

    const float4 zero = make_float4(0.f, 0.f, 0.f, 0.f);

    // zero invalid halo rows once (never staged over; own-wave r/w only)
    if (v0) {
        *(fx4*)(&lds[wb + 1536 + (lane << 2)])       = (fx4)0.0f;
        *(fx4*)(&lds[wb + 1536 + 512 + (lane << 2)]) = (fx4)0.0f;
    }
    if (v15) {
        *(fx4*)(&lds[wb + 1536 + 256 + (lane << 2)])       = (fx4)0.0f;
        *(fx4*)(&lds[wb + 1536 + 512 + 256 + (lane << 2)]) = (fx4)0.0f;
    }

    if (chunk == 0) {
        PROLOGUE(0)
        S0(0,3,1,1,0)  S1(1,4,1,1,0)  S2(2,4,1,1,0)  S3(3,4,1,1,0)
        S4(4,4,1,1,0)  S5(5,4,1,1,0)  S6(6,4,1,1,0)  S7(7,4,1,1,0)
        S0(8,4,1,1,0)  S1(9,4,1,1,0)  S2(10,4,1,1,0) S3(11,4,1,1,0)
        S4(12,4,1,1,0) S5(13,4,1,1,0) S6(14,4,1,1,0) S7(15,4,1,1,0)
        S0(16,4,1,1,0) S1(17,4,1,1,0) S2(18,4,1,1,0) S3(19,4,1,1,0)
        S4(20,4,1,1,0) S5(21,4,1,1,0) S6(22,4,1,1,0) S7(23,4,1,1,0)
        S0(24,4,1,1,0) S1(25,4,1,1,0) S2(26,4,1,1,0) S3(27,4,1,1,0)
        S4(28,4,1,1,0) S5(29,4,1,1,0) S6(30,4,1,1,0) S7(31,1,0,0,0)
    } else {
        PROLOGUE(32)
        S0(32,3,1,1,0) S1(33,4,1,1,0) S2(34,4,1,1,0) S3(35,4,1,1,0)
        S4(36,4,1,1,0) S5(37,4,1,1,0) S6(38,4,1,1,0) S7(39,4,1,1,0)
        S0(40,4,1,1,0) S1(41,4,1,1,0) S2(42,4,1,1,0) S3(43,4,1,1,0)
        S4(44,4,1,1,0) S5(45,4,1,1,0) S6(46,4,1,1,0) S7(47,4,1,1,0)
        S0(48,4,1,1,0) S1(49,4,1,1,0) S2(50,4,1,1,0) S3(51,4,1,1,0)
        S4(52,4,1,1,0) S5(53,4,1,1,0) S6(54,4,1,1,0) S7(55,4,1,1,0)
        S0(56,4,1,1,0) S1(57,4,1,1,0) S2(58,4,1,1,0) S3(59,3,0,1,0)
        S4(60,3,0,1,1) S5(61,3,0,1,1) S6(62,3,0,1,1) S7(63,1,0,0,1)
    }
}

extern "C" void kernel_launch(void* const* d_in, const int* in_sizes, int n_in,
                              void* d_out, int out_size, void* d_ws, size_t ws_size,
                              hipStream_t stream) {
    const float* x = (const float*)d_in[0];
    const float* p = (const float*)d_in[1];
    float* out = (float*)d_out;
    lap3d_nobar<<<256, 1024, 0, stream>>>(x, p, out);
}

// Round 19
// 46.565 us; speedup vs baseline: 1.2252x; 1.2252x over previous
//
#include <hip/hip_runtime.h>

// Laplacian3D: full-plane LDS ring (10 slots = 160 KiB) + named-register
// z-ring + counted vmcnt + 4-STEP BARRIER GROUPS (9 barriers; R17 had 17,
// R16 33). Prefetch distance 6: GLD(z+6) at step z overwrites the slot of
// plane z-4, whose last read (center taps, step z-4) is always in the
// PREVIOUS 4-step group -> the inter-group barrier orders it, all phases.
// vmcnt (1 GLD + 1 store per wave per step): fill plane z+4's GLD issued at
// step z-2 -> 4 newer ops at step z's wait -> steady VMW(4); ramp 2,3;
// tails 3,2 then no-op. Cross-wave y-taps of plane z (staged @z-6) are
// retired by the issuing wave's VMW(4) at z-4, before the inter-group
// barrier preceding step z. Prologue: 6 GLDs + VMW(2) (planes 0..3 landed
// before the single prologue barrier -> group-0 cross-wave reads safe).

#define NSLOT 10
#define PLANEF 4096   // 64*64 floats = 16 KB
#define CHUNK 32

typedef float fx4 __attribute__((ext_vector_type(4)));

#define GLD(gsrc, ldst) __builtin_amdgcn_global_load_lds(                      \
    (const __attribute__((address_space(1))) unsigned int*)(gsrc),             \
    (__attribute__((address_space(3))) unsigned int*)(ldst), 16, 0, 0)

#define VMW(N) asm volatile("s_waitcnt vmcnt(" #N ")" ::: "memory")

#define F4E(v, j) ((j) == 0 ? (v).x : (j) == 1 ? (v).y : (j) == 2 ? (v).z : (v).w)

// One z-step. A0 = plane Z0+IZ-4 on entry, Z0+IZ+4 on exit (ring fill).
// NW = vmcnt immediate (63 = no-op), HG = issue GLD(z+6), BR = barrier after.
#define STEP(Z0, IZ, NW, HG, BR, A0, A1, A2, A3, A4, A5, A6, A7)               \
  {                                                                            \
    if (HG)                                                                    \
        GLD(vol + (size_t)((Z0) + (IZ) + 6) * PLANEF + foff,                   \
            &lds[((Z0) + (IZ) + 6) % NSLOT][wbase]);                           \
    VMW(NW);                                                                   \
    const float4 zm4 = A0;                                                     \
    A0 = ((Z0) + (IZ) + 4 < 64)                                                \
         ? *(const float4*)(&lds[((Z0) + (IZ) + 4) % NSLOT][foff]) : zero;     \
    const float4 zp4 = A0;                                                     \
    const float4 zm2 = A2, zm1 = A3, ctr = A4, zp1 = A5, zp2 = A6;             \
    const float* plz = &lds[((Z0) + (IZ)) % NSLOT][0];                         \
    const float4 wm = *(const float4*)(plz + wmoff);                           \
    const float4 wp = *(const float4*)(plz + wpoff);                           \
    const float4 ym4t = *(const float4*)(plz + yoff[0]);                       \
    const float4 ym2t = *(const float4*)(plz + yoff[1]);                       \
    const float4 ym1t = *(const float4*)(plz + yoff[2]);                       \
    const float4 yp1t = *(const float4*)(plz + yoff[3]);                       \
    const float4 yp2t = *(const float4*)(plz + yoff[4]);                       \
    const float4 yp4t = *(const float4*)(plz + yoff[5]);                       \
    const float win[12] = {wm.x * wmm, wm.y * wmm, wm.z * wmm, wm.w * wmm,     \
                           ctr.x, ctr.y, ctr.z, ctr.w,                         \
                           wp.x * wpm, wp.y * wpm, wp.z * wpm, wp.w * wpm};    \
    fx4 o;                                                                     \
    _Pragma("unroll")                                                          \
    for (int j = 0; j < 4; ++j) {                                              \
        const float s1 = F4E(zm1, j) + F4E(zp1, j) + win[3 + j] + win[5 + j]   \
                       + ym[2] * F4E(ym1t, j) + ym[3] * F4E(yp1t, j);          \
        const float s2 = F4E(zm2, j) + F4E(zp2, j) + win[2 + j] + win[6 + j]   \
                       + ym[1] * F4E(ym2t, j) + ym[4] * F4E(yp2t, j);          \
        const float s4 = F4E(zm4, j) + F4E(zp4, j) + win[j] + win[8 + j]       \
                       + ym[0] * F4E(ym4t, j) + ym[5] * F4E(yp4t, j);          \
        o[j] = km6 * win[4 + j] + k1 * s1 + k2 * s2 + k4 * s4;                 \
    }                                                                          \
    __builtin_nontemporal_store(                                               \
        o, (fx4*)(ovol + (size_t)((Z0) + (IZ)) * PLANEF + foff));              \
    if (BR) __builtin_amdgcn_s_barrier();                                      \
  }

// rotation wrappers (ring period 8)
#define S0(Z0,IZ,NW,HG,BR) STEP(Z0,IZ,NW,HG,BR, a0,a1,a2,a3,a4,a5,a6,a7)
#define S1(Z0,IZ,NW,HG,BR) STEP(Z0,IZ,NW,HG,BR, a1,a2,a3,a4,a5,a6,a7,a0)
#define S2(Z0,IZ,NW,HG,BR) STEP(Z0,IZ,NW,HG,BR, a2,a3,a4,a5,a6,a7,a0,a1)
#define S3(Z0,IZ,NW,HG,BR) STEP(Z0,IZ,NW,HG,BR, a3,a4,a5,a6,a7,a0,a1,a2)
#define S4(Z0,IZ,NW,HG,BR) STEP(Z0,IZ,NW,HG,BR, a4,a5,a6,a7,a0,a1,a2,a3)
#define S5(Z0,IZ,NW,HG,BR) STEP(Z0,IZ,NW,HG,BR, a5,a6,a7,a0,a1,a2,a3,a4)
#define S6(Z0,IZ,NW,HG,BR) STEP(Z0,IZ,NW,HG,BR, a6,a7,a0,a1,a2,a3,a4,a5)
#define S7(Z0,IZ,NW,HG,BR) STEP(Z0,IZ,NW,HG,BR, a7,a0,a1,a2,a3,a4,a5,a6)

// prologue: register-ring init (planes Z0-4..Z0+3 from global), 6 GLDs
// (planes Z0..Z0+5), VMW(2) -> planes Z0..Z0+3 landed, one raw barrier.
#define PROLOGUE(Z0)                                                           \
    float4 a0, a1, a2, a3, a4, a5, a6, a7;                                     \
    {                                                                          \
        float4* rr[8] = {&a0, &a1, &a2, &a3, &a4, &a5, &a6, &a7};              \
        _Pragma("unroll")                                                      \
        for (int i = 0; i < 8; ++i)                                            \
            *rr[i] = ((Z0) - 4 + i >= 0)                                       \
                ? *(const float4*)(vol + (size_t)((Z0) - 4 + i) * PLANEF + foff) \
                : zero;                                                        \
    }                                                                          \
    _Pragma("unroll")                                                          \
    for (int i = 0; i < 6; ++i)                                                \
        GLD(vol + (size_t)((Z0) + i) * PLANEF + foff,                          \
            &lds[((Z0) + i) % NSLOT][wbase]);                                  \
    VMW(2);                                                                    \
    __builtin_amdgcn_s_barrier();

__global__ __launch_bounds__(1024) void lap3d_g4(
    const float* __restrict__ x, const float* __restrict__ p,
    float* __restrict__ out)
{
    __shared__ __align__(16) float lds[NSLOT][PLANEF];   // 163840 B

    const int tid   = threadIdx.x;
    const int bc    = blockIdx.x & 127;       // b*64 + c
    const int chunk = blockIdx.x >> 7;        // chunk pairs 128 apart: same XCD
    const int c     = bc & 63;

    const float* vol  = x   + (size_t)bc * (64 * PLANEF);
    float*       ovol = out + (size_t)bc * (64 * PLANEF);

    const int y     = tid >> 4;
    const int w0    = (tid & 15) << 2;
    const int foff  = tid << 2;               // y*64 + w0
    const int wbase = (tid >> 6) << 8;        // wave's float base in a plane

    const float k1  = 0.25f / (1.0f + __expf(-p[c]));
    const float k2  = 0.25f / (1.0f + __expf(-p[64 + c]));
    const float k4  = 0.25f / (1.0f + __expf(-p[128 + c]));
    const float km6 = -6.0f * (k1 + k2 + k4);

    // y-tap clamped offsets + masks
    const int dys[6] = {-4, -2, -1, 1, 2, 4};
    int yoff[6]; float ym[6];
#pragma unroll
    for (int k = 0; k < 6; ++k) {
        const int yy = y + dys[k];
        const bool v = (unsigned)yy < 64u;
        yoff[k] = (v ? yy : y) * 64 + w0;
        ym[k]   = v ? 1.0f : 0.0f;
    }
    // w-tap clamped offsets + masks (quad-aligned)
    const bool  wmv = (w0 >= 4), wpv = (w0 <= 56);
    const int   wmoff = wmv ? foff - 4 : foff;
    const int   wpoff = wpv ? foff + 4 : foff;
    const float wmm = wmv ? 1.0f : 0.0f, wpm = wpv ? 1.0f : 0.0f;

    const float4 zero = make_float4(0.f, 0.f, 0.f, 0.f);

    if (chunk == 0) {
        PROLOGUE(0)
        // staging: GLD(z+6) while z+6 <= 35 (last fill plane), i.e. z <= 29
        S0(0, 0,2,1,0)  S1(0, 1,3,1,0)  S2(0, 2,4,1,0)  S3(0, 3,4,1,1)
        S4(0, 4,4,1,0)  S5(0, 5,4,1,0)  S6(0, 6,4,1,0)  S7(0, 7,4,1,1)
        S0(0, 8,4,1,0)  S1(0, 9,4,1,0)  S2(0,10,4,1,0)  S3(0,11,4,1,1)
        S4(0,12,4,1,0)  S5(0,13,4,1,0)  S6(0,14,4,1,0)  S7(0,15,4,1,1)
        S0(0,16,4,1,0)  S1(0,17,4,1,0)  S2(0,18,4,1,0)  S3(0,19,4,1,1)
        S4(0,20,4,1,0)  S5(0,21,4,1,0)  S6(0,22,4,1,0)  S7(0,23,4,1,1)
        S0(0,24,4,1,0)  S1(0,25,4,1,0)  S2(0,26,4,1,0)  S3(0,27,4,1,1)
        S4(0,28,4,1,0)  S5(0,29,4,1,0)  S6(0,30,3,0,0)  S7(0,31,2,0,0)
    } else {
        PROLOGUE(32)
        // staging: GLD(z+6) while z+6 <= 63, i.e. z <= 57
        S0(32, 0,2,1,0)  S1(32, 1,3,1,0)  S2(32, 2,4,1,0)  S3(32, 3,4,1,1)
        S4(32, 4,4,1,0)  S5(32, 5,4,1,0)  S6(32, 6,4,1,0)  S7(32, 7,4,1,1)
        S0(32, 8,4,1,0)  S1(32, 9,4,1,0)  S2(32,10,4,1,0)  S3(32,11,4,1,1)
        S4(32,12,4,1,0)  S5(32,13,4,1,0)  S6(32,14,4,1,0)  S7(32,15,4,1,1)
        S0(32,16,4,1,0)  S1(32,17,4,1,0)  S2(32,18,4,1,0)  S3(32,19,4,1,1)
        S4(32,20,4,1,0)  S5(32,21,4,1,0)  S6(32,22,4,1,0)  S7(32,23,4,1,1)
        S0(32,24,4,1,0)  S1(32,25,4,1,0)  S2(32,26,3,0,0)  S3(32,27,2,0,1)
        S4(32,28,63,0,0) S5(32,29,63,0,0) S6(32,30,63,0,0) S7(32,31,63,0,0)
    }
}

extern "C" void kernel_launch(void* const* d_in, const int* in_sizes, int n_in,
                              void* d_out, int out_size, void* d_ws, size_t ws_size,
                              hipStream_t stream) {
    const float* x = (const float*)d_in[0];
    const float* p = (const float*)d_in[1];
    float* out = (float*)d_out;
    lap3d_g4<<<256, 1024, 0, stream>>>(x, p, out);
}

// Round 20
// 44.860 us; speedup vs baseline: 1.2718x; 1.0380x over previous
//
#include <hip/hip_runtime.h>

// Laplacian3D: R17 structure (10-slot full-plane LDS ring, named-register
// z-ring, counted vmcnt, paired-step barriers = 17) + DPP w-taps.
// w-window = lane±1's center register via v_mov_dpp row_shr:1 / row_shl:1
// (16-lane DPP rows == our 16-lane y-rows), bound_ctrl=1 zero-fills at row
// edges -> replaces 2 ds_read_b128 AND the w-masks. DS reads: 9 -> 7/step.
// Sync schedule identical to R17: prefetch distance 8, steady VMW(8),
// ramp 4,5,6,7, tails 7,6,5,4; barrier after odd steps only.

#define NSLOT 10
#define PLANEF 4096   // 64*64 floats = 16 KB
#define CHUNK 32

typedef float fx4 __attribute__((ext_vector_type(4)));

#define GLD(gsrc, ldst) __builtin_amdgcn_global_load_lds(                      \
    (const __attribute__((address_space(1))) unsigned int*)(gsrc),             \
    (__attribute__((address_space(3))) unsigned int*)(ldst), 16, 0, 0)

#define VMW(N) asm volatile("s_waitcnt vmcnt(" #N ")" ::: "memory")

#define F4E(v, j) ((j) == 0 ? (v).x : (j) == 1 ? (v).y : (j) == 2 ? (v).z : (v).w)

// DPP neighbor fetch within 16-lane rows; bound_ctrl=1 -> 0 at row edge.
#define DPP_SHR1(v) __int_as_float(__builtin_amdgcn_update_dpp(                \
    0, __float_as_int(v), 0x111, 0xF, 0xF, true))   // lane i <- lane i-1
#define DPP_SHL1(v) __int_as_float(__builtin_amdgcn_update_dpp(                \
    0, __float_as_int(v), 0x101, 0xF, 0xF, true))   // lane i <- lane i+1

// One z-step. A0 = plane Z0+IZ-4 on entry, Z0+IZ+4 on exit (ring fill).
// NW = vmcnt immediate (63 = no-op), HG = issue GLD(z+8), BR = barrier after.
#define STEP(Z0, IZ, NW, HG, BR, A0, A1, A2, A3, A4, A5, A6, A7)               \
  {                                                                            \
    if (HG)                                                                    \
        GLD(vol + (size_t)((Z0) + (IZ) + 8) * PLANEF + foff,                   \
            &lds[((Z0) + (IZ) + 8) % NSLOT][wbase]);                           \
    VMW(NW);                                                                   \
    const float4 zm4 = A0;                                                     \
    A0 = ((Z0) + (IZ) + 4 < 64)                                                \
         ? *(const float4*)(&lds[((Z0) + (IZ) + 4) % NSLOT][foff]) : zero;     \
    const float4 zp4 = A0;                                                     \
    const float4 zm2 = A2, zm1 = A3, ctr = A4, zp1 = A5, zp2 = A6;             \
    const float* plz = &lds[((Z0) + (IZ)) % NSLOT][0];                         \
    const float4 ym4t = *(const float4*)(plz + yoff[0]);                       \
    const float4 ym2t = *(const float4*)(plz + yoff[1]);                       \
    const float4 ym1t = *(const float4*)(plz + yoff[2]);                       \
    const float4 yp1t = *(const float4*)(plz + yoff[3]);                       \
    const float4 yp2t = *(const float4*)(plz + yoff[4]);                       \
    const float4 yp4t = *(const float4*)(plz + yoff[5]);                       \
    const float win[12] = {DPP_SHR1(ctr.x), DPP_SHR1(ctr.y),                   \
                           DPP_SHR1(ctr.z), DPP_SHR1(ctr.w),                   \
                           ctr.x, ctr.y, ctr.z, ctr.w,                         \
                           DPP_SHL1(ctr.x), DPP_SHL1(ctr.y),                   \
                           DPP_SHL1(ctr.z), DPP_SHL1(ctr.w)};                  \
    fx4 o;                                                                     \
    _Pragma("unroll")                                                          \
    for (int j = 0; j < 4; ++j) {                                              \
        const float s1 = F4E(zm1, j) + F4E(zp1, j) + win[3 + j] + win[5 + j]   \
                       + ym[2] * F4E(ym1t, j) + ym[3] * F4E(yp1t, j);          \
        const float s2 = F4E(zm2, j) + F4E(zp2, j) + win[2 + j] + win[6 + j]   \
                       + ym[1] * F4E(ym2t, j) + ym[4] * F4E(yp2t, j);          \
        const float s4 = F4E(zm4, j) + F4E(zp4, j) + win[j] + win[8 + j]       \
                       + ym[0] * F4E(ym4t, j) + ym[5] * F4E(yp4t, j);          \
        o[j] = km6 * win[4 + j] + k1 * s1 + k2 * s2 + k4 * s4;                 \
    }                                                                          \
    __builtin_nontemporal_store(                                               \
        o, (fx4*)(ovol + (size_t)((Z0) + (IZ)) * PLANEF + foff));              \
    if (BR) __builtin_amdgcn_s_barrier();                                      \
  }

// rotation wrappers (ring period 8)
#define S0(Z0,IZ,NW,HG,BR) STEP(Z0,IZ,NW,HG,BR, a0,a1,a2,a3,a4,a5,a6,a7)
#define S1(Z0,IZ,NW,HG,BR) STEP(Z0,IZ,NW,HG,BR, a1,a2,a3,a4,a5,a6,a7,a0)
#define S2(Z0,IZ,NW,HG,BR) STEP(Z0,IZ,NW,HG,BR, a2,a3,a4,a5,a6,a7,a0,a1)
#define S3(Z0,IZ,NW,HG,BR) STEP(Z0,IZ,NW,HG,BR, a3,a4,a5,a6,a7,a0,a1,a2)
#define S4(Z0,IZ,NW,HG,BR) STEP(Z0,IZ,NW,HG,BR, a4,a5,a6,a7,a0,a1,a2,a3)
#define S5(Z0,IZ,NW,HG,BR) STEP(Z0,IZ,NW,HG,BR, a5,a6,a7,a0,a1,a2,a3,a4)
#define S6(Z0,IZ,NW,HG,BR) STEP(Z0,IZ,NW,HG,BR, a6,a7,a0,a1,a2,a3,a4,a5)
#define S7(Z0,IZ,NW,HG,BR) STEP(Z0,IZ,NW,HG,BR, a7,a0,a1,a2,a3,a4,a5,a6)

// prologue: ring-init reg loads (planes Z0-4..Z0+3), 8 GLDs (Z0..Z0+7),
// VMW(4) (planes Z0..Z0+3 landed -> step-0/1 taps safe via prologue barrier).
#define PROLOGUE(Z0)                                                           \
    float4 a0, a1, a2, a3, a4, a5, a6, a7;                                     \
    {                                                                          \
        float4* rr[8] = {&a0, &a1, &a2, &a3, &a4, &a5, &a6, &a7};              \
        _Pragma("unroll")                                                      \
        for (int i = 0; i < 8; ++i)                                            \
            *rr[i] = ((Z0) - 4 + i >= 0)                                       \
                ? *(const float4*)(vol + (size_t)((Z0) - 4 + i) * PLANEF + foff) \
                : zero;                                                        \
    }                                                                          \
    _Pragma("unroll")                                                          \
    for (int i = 0; i < 8; ++i)                                                \
        GLD(vol + (size_t)((Z0) + i) * PLANEF + foff,                          \
            &lds[((Z0) + i) % NSLOT][wbase]);                                  \
    VMW(4);                                                                    \
    __builtin_amdgcn_s_barrier();

__global__ __launch_bounds__(1024) void lap3d_dpp(
    const float* __restrict__ x, const float* __restrict__ p,
    float* __restrict__ out)
{
    __shared__ __align__(16) float lds[NSLOT][PLANEF];   // 163840 B

    const int tid   = threadIdx.x;
    const int bc    = blockIdx.x & 127;       // b*64 + c
    const int chunk = blockIdx.x >> 7;        // chunk pairs 128 apart: same XCD
    const int c     = bc & 63;

    const float* vol  = x   + (size_t)bc * (64 * PLANEF);
    float*       ovol = out + (size_t)bc * (64 * PLANEF);

    const int y     = tid >> 4;
    const int w0    = (tid & 15) << 2;
    const int foff  = tid << 2;               // y*64 + w0
    const int wbase = (tid >> 6) << 8;        // wave's float base in a plane

    const float k1  = 0.25f / (1.0f + __expf(-p[c]));
    const float k2  = 0.25f / (1.0f + __expf(-p[64 + c]));
    const float k4  = 0.25f / (1.0f + __expf(-p[128 + c]));
    const float km6 = -6.0f * (k1 + k2 + k4);

    // y-tap clamped offsets + masks
    const int dys[6] = {-4, -2, -1, 1, 2, 4};
    int yoff[6]; float ym[6];
#pragma unroll
    for (int k = 0; k < 6; ++k) {
        const int yy = y + dys[k];
        const bool v = (unsigned)yy < 64u;
        yoff[k] = (v ? yy : y) * 64 + w0;
        ym[k]   = v ? 1.0f : 0.0f;
    }

    const float4 zero = make_float4(0.f, 0.f, 0.f, 0.f);

    if (chunk == 0) {
        PROLOGUE(0)
        S0(0, 0,4,1,0)  S1(0, 1,5,1,1)  S2(0, 2,6,1,0)  S3(0, 3,7,1,1)
        S4(0, 4,8,1,0)  S5(0, 5,8,1,1)  S6(0, 6,8,1,0)  S7(0, 7,8,1,1)
        S0(0, 8,8,1,0)  S1(0, 9,8,1,1)  S2(0,10,8,1,0)  S3(0,11,8,1,1)
        S4(0,12,8,1,0)  S5(0,13,8,1,1)  S6(0,14,8,1,0)  S7(0,15,8,1,1)
        S0(0,16,8,1,0)  S1(0,17,8,1,1)  S2(0,18,8,1,0)  S3(0,19,8,1,1)
        S4(0,20,8,1,0)  S5(0,21,8,1,1)  S6(0,22,8,1,0)  S7(0,23,8,1,1)
        S0(0,24,8,1,0)  S1(0,25,8,1,1)  S2(0,26,8,1,0)  S3(0,27,8,1,1)
        S4(0,28,7,0,0)  S5(0,29,6,0,1)  S6(0,30,5,0,0)  S7(0,31,4,0,0)
    } else {
        PROLOGUE(32)
        S0(32, 0,4,1,0)  S1(32, 1,5,1,1)  S2(32, 2,6,1,0)  S3(32, 3,7,1,1)
        S4(32, 4,8,1,0)  S5(32, 5,8,1,1)  S6(32, 6,8,1,0)  S7(32, 7,8,1,1)
        S0(32, 8,8,1,0)  S1(32, 9,8,1,1)  S2(32,10,8,1,0)  S3(32,11,8,1,1)
        S4(32,12,8,1,0)  S5(32,13,8,1,1)  S6(32,14,8,1,0)  S7(32,15,8,1,1)
        S0(32,16,8,1,0)  S1(32,17,8,1,1)  S2(32,18,8,1,0)  S3(32,19,8,1,1)
        S4(32,20,8,1,0)  S5(32,21,8,1,1)  S6(32,22,8,1,0)  S7(32,23,8,1,1)
        S0(32,24,7,0,0)  S1(32,25,6,0,1)  S2(32,26,5,0,0)  S3(32,27,4,0,1)
        S4(32,28,63,0,0) S5(32,29,63,0,1) S6(32,30,63,0,0) S7(32,31,63,0,0)
    }
}

extern "C" void kernel_launch(void* const* d_in, const int* in_sizes, int n_in,
                              void* d_out, int out_size, void* d_ws, size_t ws_size,
                              hipStream_t stream) {
    const float* x = (const float*)d_in[0];
    const float* p = (const float*)d_in[1];
    float* out = (float*)d_out;
    lap3d_dpp<<<256, 1024, 0, stream>>>(x, p, out);
}